// Round 7
// baseline (347.197 us; speedup 1.0000x reference)
//
#include <hip/hip_runtime.h>

#define FIELDS  100000
#define FACTORS 16
#define BATCH   1024
#define FS      256                        // fields per slice
#define NS      ((FIELDS + FS - 1) / FS)   // 391 slices
#define SB      4                          // batch splits
#define RPB     (BATCH / SB)               // 256 rows per block
#define RT      8                          // rows per tile
#define NT      (RPB / RT)                 // 32 tiles per block
#define BLOCK   256
#define NBUF    3
#define NG      8                          // qpart accumulation groups

typedef __attribute__((address_space(1))) const void gvoid;
typedef __attribute__((address_space(3))) void lvoid;

// Field-major: block = (field slice, batch quarter). W quarter held in REGS
// for the whole kernel (W read once from HBM: 26 MB total vs 800 MB re-read
// in the chunk-major versions). x0 streamed via 3-deep global_load_lds
// pipeline, counted vmcnt (every wave issues exactly 1 atomic per tile, so
// counts are wave-uniform).
__global__ __launch_bounds__(BLOCK, 4) void fm_partial(
    const int* __restrict__ x0, const float* __restrict__ W,
    float* __restrict__ qparts)
{
    __shared__ __align__(16) int xbuf[NBUF][RT][FS];   // 24 KB
    __shared__ float red[4][4][RT][17];                // 8.5 KB

    const int t     = threadIdx.x;
    const int bid   = blockIdx.x;
    const int slice = bid >> 2;              // 0..390
    const int bq    = bid & 3;               // batch quarter
    const int fbeg  = slice * FS;
    const int flim  = min(FS, FIELDS - fbeg);
    const int b0    = bq * RPB;
    const int g     = slice & (NG - 1);

    const int qr   = t & 3;                  // factor quarter
    const int pg   = t >> 2;                 // field slot 0..63
    const int lane = t & 63;
    const int wv   = t >> 6;

    // ---- W quarters -> registers (read once); tail fields zeroed ----
    float4 wq[4];
    float  rs[4];
#pragma unroll
    for (int j = 0; j < 4; ++j) {
        const int  fr = pg + 64 * j;
        const bool v  = (fr < flim);
        const int  fi = fbeg + (v ? fr : 0);
        float4 w = *reinterpret_cast<const float4*>(W + (size_t)fi * FACTORS + qr * 4);
        if (!v) { w.x = 0.f; w.y = 0.f; w.z = 0.f; w.w = 0.f; }
        wq[j] = w;
        float s = w.x*w.x + w.y*w.y + w.z*w.z + w.w*w.w;   // quarter ssq
        s += __shfl_xor(s, 1);
        s += __shfl_xor(s, 2);                              // full-row ssq
        rs[j] = s;
    }

    const char*  x0b  = (const char*)x0;
    const size_t XMAX = (size_t)BATCH * FIELDS * 4 - 16;

    // wave wv stages tile rows {wv, wv+4}; 1 KB (one row) per wave per instr
    auto STAGE = [&](int buf, int tile) {
#pragma unroll
        for (int i = 0; i < 2; ++i) {
            const int row = b0 + tile * RT + i * 4 + wv;
            size_t src = ((size_t)row * FIELDS + fbeg) * 4 + (size_t)lane * 16;
            if (src > XMAX) src = XMAX;    // tail clamp; garbage masked by wq==0
            __builtin_amdgcn_global_load_lds((gvoid*)(x0b + src),
                (lvoid*)((char*)(&xbuf[buf][0][0]) + lane * 16 + wv * 1024 + i * 4096),
                16, 0, 0);
        }
    };

    STAGE(0, 0);
    STAGE(1, 1);

    for (int tl = 0; tl < NT; ++tl) {
        // counted waits: steady-state queue = S(tl+1)[2] S(tl+2)[2] A(tl-1)[1]
        if      (tl == 0)     asm volatile("s_waitcnt vmcnt(2)" ::: "memory");
        else if (tl < NT - 1) asm volatile("s_waitcnt vmcnt(3)" ::: "memory");
        else                  asm volatile("s_waitcnt vmcnt(0)" ::: "memory");
        __builtin_amdgcn_s_barrier();
        __builtin_amdgcn_sched_barrier(0);

        const int buf = tl % NBUF;
        float acc[RT][4], qac[RT];
#pragma unroll
        for (int r = 0; r < RT; ++r) {
            const float m0 = (float)xbuf[buf][r][pg];       // x0 in {0,1}
            qac[r]    = m0 * rs[0];
            acc[r][0] = m0 * wq[0].x;
            acc[r][1] = m0 * wq[0].y;
            acc[r][2] = m0 * wq[0].z;
            acc[r][3] = m0 * wq[0].w;
#pragma unroll
            for (int j = 1; j < 4; ++j) {
                const float m = (float)xbuf[buf][r][pg + 64 * j];
                qac[r]    = fmaf(m, rs[j],   qac[r]);
                acc[r][0] = fmaf(m, wq[j].x, acc[r][0]);
                acc[r][1] = fmaf(m, wq[j].y, acc[r][1]);
                acc[r][2] = fmaf(m, wq[j].z, acc[r][2]);
                acc[r][3] = fmaf(m, wq[j].w, acc[r][3]);
            }
        }
        __builtin_amdgcn_sched_barrier(0);
        __builtin_amdgcn_s_barrier();                 // all waves done with buf
        if (tl + 2 < NT) STAGE((tl + 2) % NBUF, tl + 2);

        // partial reduce over field-slots: xor 4,8 -> 4 pw-groups remain
#pragma unroll
        for (int r = 0; r < RT; ++r) {
            acc[r][0] += __shfl_xor(acc[r][0], 4);
            acc[r][1] += __shfl_xor(acc[r][1], 4);
            acc[r][2] += __shfl_xor(acc[r][2], 4);
            acc[r][3] += __shfl_xor(acc[r][3], 4);
            qac[r]    += __shfl_xor(qac[r],    4);
            acc[r][0] += __shfl_xor(acc[r][0], 8);
            acc[r][1] += __shfl_xor(acc[r][1], 8);
            acc[r][2] += __shfl_xor(acc[r][2], 8);
            acc[r][3] += __shfl_xor(acc[r][3], 8);
            qac[r]    += __shfl_xor(qac[r],    8);
        }
        if ((lane & 12) == 0) {                       // 16 lanes: 4 pgrp x 4 qr
            const int pgrp = lane >> 4;
#pragma unroll
            for (int r = 0; r < RT; ++r) {
                red[wv][pgrp][r][qr * 4 + 0] = acc[r][0];
                red[wv][pgrp][r][qr * 4 + 1] = acc[r][1];
                red[wv][pgrp][r][qr * 4 + 2] = acc[r][2];
                red[wv][pgrp][r][qr * 4 + 3] = acc[r][3];
                if (qr == 0) red[wv][pgrp][r][16] = qac[r];  // q identical in qr lanes
            }
        }
        __syncthreads();

        // flush: 34 values per wave so EVERY wave issues exactly 1 atomic
        const int fi2 = wv * 34 + lane;               // 0..135 (RT*17=136)
        if (lane < 34 && fi2 < RT * 17) {
            const int r  = fi2 / 17;
            const int jj = fi2 % 17;
            float v = 0.f;
#pragma unroll
            for (int w2 = 0; w2 < 4; ++w2)
#pragma unroll
                for (int p2 = 0; p2 < 4; ++p2)
                    v += red[w2][p2][r][jj];
            atomicAdd(&qparts[((size_t)(b0 + tl * RT + r) * NG + g) * 17 + jj], v);
        }
    }
}

__global__ __launch_bounds__(BLOCK) void fm_final(
    const float* __restrict__ qparts, float* __restrict__ out)
{
    const int b = blockIdx.x * BLOCK + threadIdx.x;
    if (b < BATCH) {
        const float* pbase = qparts + (size_t)b * NG * 17;
        float s[17];
#pragma unroll
        for (int j = 0; j < 17; ++j) s[j] = 0.f;
#pragma unroll
        for (int c = 0; c < NG; ++c)
#pragma unroll
            for (int j = 0; j < 17; ++j) s[j] += pbase[c * 17 + j];
        float ss = 0.f;
#pragma unroll
        for (int k = 0; k < FACTORS; ++k) ss += s[k] * s[k];
        out[b] = 0.5f * (ss - s[16]);
    }
}

extern "C" void kernel_launch(void* const* d_in, const int* in_sizes, int n_in,
                              void* d_out, int out_size, void* d_ws, size_t ws_size,
                              hipStream_t stream)
{
    const int*   x0 = (const int*)d_in[0];
    const float* W  = (const float*)d_in[1];
    float* out    = (float*)d_out;
    float* qparts = (float*)d_ws;   // [1024][NG][17] floats = 557 KB

    hipMemsetAsync(qparts, 0, (size_t)BATCH * NG * 17 * sizeof(float), stream);
    fm_partial<<<dim3(NS * SB), dim3(BLOCK), 0, stream>>>(x0, W, qparts);
    fm_final<<<dim3((BATCH + BLOCK - 1) / BLOCK), dim3(BLOCK), 0, stream>>>(qparts, out);
}

// Round 8
// 173.314 us; speedup vs baseline: 2.0033x; 2.0033x over previous
//
#include <hip/hip_runtime.h>

#define FIELDS  100000
#define FACTORS 16
#define BATCH   1024
#define BT      4                      // batch rows per block
#define NCHUNK  8                      // chunk == bid&7 -> XCD-pinned W slice
#define FPC     (FIELDS / NCHUNK)      // 12500
#define BLOCK   256
#define FPI     256                    // fields per block-iteration
#define NMAIN   (FPC / FPI)            // 48 full iterations
#define TAILP   ((FPC - NMAIN * FPI) / 4)   // 53 valid pg-groups in tail (212 fields)

// Lane (qr = t&3, pg = t>>2): 4 consecutive fields (pg*4..+3), factor quarter qr.
// x0: int4 per row (4-dup across qr merges in coalescer -> 256B unique/wave-instr).
// W:  4 b128 loads/iter; each 64B line (one field's 16 factors) fully consumed
//     by its 4 qr lanes. ssq per-quarter in-register (q-reduce needs no scaling).
// x0 double-buffered in named int4 regs (A/B), one reduce at kernel end.
__global__ __launch_bounds__(BLOCK, 4) void fm_partial(
    const int* __restrict__ x0, const float* __restrict__ W,
    float* __restrict__ ws)
{
    const int t     = threadIdx.x;
    const int bid   = blockIdx.x;
    const int rg    = bid >> 3;              // 0..255
    const int chunk = bid & (NCHUNK - 1);    // 0..7
    const int b0    = rg * BT;
    const int fbeg  = chunk * FPC;

    const int qr = t & 3;
    const int pg = t >> 2;                   // 0..63

    float acc[BT][4];
    float qac[BT];
#pragma unroll
    for (int r = 0; r < BT; ++r) {
        qac[r] = 0.f;
#pragma unroll
        for (int j = 0; j < 4; ++j) acc[r][j] = 0.f;
    }

    const char* x0b = (const char*)x0;
    const char* Wb  = (const char*)W;

    // 32-bit byte offsets (x0 total 409.6MB < 4GB). xrow* are block-uniform -> SGPR.
    const unsigned xrow0 = (unsigned)b0 * (FIELDS * 4u);
    const unsigned xrow1 = xrow0 + FIELDS * 4u;
    const unsigned xrow2 = xrow1 + FIELDS * 4u;
    const unsigned xrow3 = xrow2 + FIELDS * 4u;
    const unsigned fb4   = (unsigned)(fbeg + pg * 4) * 4u;  // first int4 byte offset

#define LOADXO(v0, v1, v2, v3, xoff) do {                                  \
        v0 = *(const int4*)(x0b + (xrow0 + (xoff)));                       \
        v1 = *(const int4*)(x0b + (xrow1 + (xoff)));                       \
        v2 = *(const int4*)(x0b + (xrow2 + (xoff)));                       \
        v3 = *(const int4*)(x0b + (xrow3 + (xoff)));                       \
    } while (0)

    // W byte offset = field*64 + qr*16 = (x0 byte offset)*16 + qr*16
#define COMPUTEO(v0, v1, v2, v3, xoff) do {                                \
        const unsigned _wo = (xoff) * 16u + (unsigned)qr * 16u;            \
        const float4 w0 = *(const float4*)(Wb + _wo);                      \
        const float4 w1 = *(const float4*)(Wb + _wo + 64u);                \
        const float4 w2 = *(const float4*)(Wb + _wo + 128u);               \
        const float4 w3 = *(const float4*)(Wb + _wo + 192u);               \
        const float s0 = fmaf(w0.x, w0.x, fmaf(w0.y, w0.y, fmaf(w0.z, w0.z, w0.w * w0.w))); \
        const float s1 = fmaf(w1.x, w1.x, fmaf(w1.y, w1.y, fmaf(w1.z, w1.z, w1.w * w1.w))); \
        const float s2 = fmaf(w2.x, w2.x, fmaf(w2.y, w2.y, fmaf(w2.z, w2.z, w2.w * w2.w))); \
        const float s3 = fmaf(w3.x, w3.x, fmaf(w3.y, w3.y, fmaf(w3.z, w3.z, w3.w * w3.w))); \
        FM_ROW(v0, 0); FM_ROW(v1, 1); FM_ROW(v2, 2); FM_ROW(v3, 3);       \
    } while (0)

#define FM_ROW(xv, r) do {                                                 \
        const float m0 = (float)xv.x, m1 = (float)xv.y,                    \
                    m2 = (float)xv.z, m3 = (float)xv.w;                    \
        qac[r]    = fmaf(m0, s0,   fmaf(m1, s1,   fmaf(m2, s2,   fmaf(m3, s3,   qac[r])))); \
        acc[r][0] = fmaf(m0, w0.x, fmaf(m1, w1.x, fmaf(m2, w2.x, fmaf(m3, w3.x, acc[r][0])))); \
        acc[r][1] = fmaf(m0, w0.y, fmaf(m1, w1.y, fmaf(m2, w2.y, fmaf(m3, w3.y, acc[r][1])))); \
        acc[r][2] = fmaf(m0, w0.z, fmaf(m1, w1.z, fmaf(m2, w2.z, fmaf(m3, w3.z, acc[r][2])))); \
        acc[r][3] = fmaf(m0, w0.w, fmaf(m1, w1.w, fmaf(m2, w2.w, fmaf(m3, w3.w, acc[r][3])))); \
    } while (0)

    int4 xa0, xa1, xa2, xa3, xb0, xb1, xb2, xb3;

    LOADXO(xa0, xa1, xa2, xa3, fb4);
#pragma unroll 1
    for (int it = 0; it < NMAIN; it += 2) {
        const unsigned oA = fb4 + (unsigned)it * (FPI * 4u);
        LOADXO(xb0, xb1, xb2, xb3, oA + FPI * 4u);          // prefetch it+1
        COMPUTEO(xa0, xa1, xa2, xa3, oA);                   // consume it
        if (it + 2 < NMAIN)
            LOADXO(xa0, xa1, xa2, xa3, oA + 2u * (FPI * 4u)); // prefetch it+2
        COMPUTEO(xb0, xb1, xb2, xb3, oA + FPI * 4u);        // consume it+1
    }

    // ---- masked tail: fields [NMAIN*FPI, FPC) of the chunk (212 = 53*4) ----
    {
        const bool valid = (pg < TAILP);
        const int  pgc   = valid ? pg : (TAILP - 1);
        const unsigned to = (unsigned)(fbeg + NMAIN * FPI + pgc * 4) * 4u;
        int4 v0, v1, v2, v3;
        LOADXO(v0, v1, v2, v3, to);
        if (!valid) {                         // zero masks -> zero contribution
            v0.x = v0.y = v0.z = v0.w = 0;
            v1.x = v1.y = v1.z = v1.w = 0;
            v2.x = v2.y = v2.z = v2.w = 0;
            v3.x = v3.y = v3.z = v3.w = 0;
        }
        COMPUTEO(v0, v1, v2, v3, to);
    }

    // ---- wave reduce ----
    // acc: sum lanes sharing qr (xor 4..32). qac: sum ALL lanes — each lane
    // contributed only its own quarter's ssq, so q is counted exactly once.
#pragma unroll
    for (int r = 0; r < BT; ++r) {
#pragma unroll
        for (int off = 4; off < 64; off <<= 1) {
            acc[r][0] += __shfl_xor(acc[r][0], off);
            acc[r][1] += __shfl_xor(acc[r][1], off);
            acc[r][2] += __shfl_xor(acc[r][2], off);
            acc[r][3] += __shfl_xor(acc[r][3], off);
        }
#pragma unroll
        for (int off = 1; off < 64; off <<= 1)
            qac[r] += __shfl_xor(qac[r], off);
    }

    __shared__ float red[4][BT][17];
    const int wave = t >> 6;
    const int lane = t & 63;
    if (lane < 4) {                           // lane l holds quarter qr==l
#pragma unroll
        for (int r = 0; r < BT; ++r) {
#pragma unroll
            for (int j = 0; j < 4; ++j)
                red[wave][r][lane * 4 + j] = acc[r][j];
            if (lane == 0) red[wave][r][16] = qac[r];
        }
    }
    __syncthreads();
    if (t < BT * 17) {
        const int r = t / 17;
        const int j = t % 17;
        const float v = red[0][r][j] + red[1][r][j] + red[2][r][j] + red[3][r][j];
        ws[((size_t)(b0 + r) * NCHUNK + chunk) * 17 + j] = v;
    }
}

__global__ __launch_bounds__(BLOCK) void fm_final(
    const float* __restrict__ ws, float* __restrict__ out)
{
    const int b = blockIdx.x * BLOCK + threadIdx.x;
    if (b < BATCH) {
        const float* pbase = ws + (size_t)b * NCHUNK * 17;
        float s[17];
#pragma unroll
        for (int j = 0; j < 17; ++j) s[j] = 0.f;
#pragma unroll
        for (int c = 0; c < NCHUNK; ++c)
#pragma unroll
            for (int j = 0; j < 17; ++j) s[j] += pbase[c * 17 + j];
        float ss = 0.f;
#pragma unroll
        for (int k = 0; k < FACTORS; ++k) ss += s[k] * s[k];
        out[b] = 0.5f * (ss - s[16]);
    }
}

extern "C" void kernel_launch(void* const* d_in, const int* in_sizes, int n_in,
                              void* d_out, int out_size, void* d_ws, size_t ws_size,
                              hipStream_t stream)
{
    const int*   x0 = (const int*)d_in[0];
    const float* W  = (const float*)d_in[1];
    float* out = (float*)d_out;
    float* ws  = (float*)d_ws;   // [1024][8][17] floats, every slot written

    fm_partial<<<dim3((BATCH / BT) * NCHUNK), dim3(BLOCK), 0, stream>>>(x0, W, ws);
    fm_final<<<dim3((BATCH + BLOCK - 1) / BLOCK), dim3(BLOCK), 0, stream>>>(ws, out);
}